// Round 1
// baseline (256.330 us; speedup 1.0000x reference)
//
#include <hip/hip_runtime.h>
#include <stdint.h>

// RNN1: B=4096,T=256,E=27,H=64.
// a_{t+1} = tanh(a_t @ Waa^T + x_t @ Wax^T + ba), x_t = word[:,t-1,:] (0 at t=0)
// y[:,t,:] = a_{t+1} @ Wy^T + by
//
// Design (round 1): 256 blocks x 256 threads; 16 batch rows per block; wave wv
// owns hidden N-tile [16wv,16wv+16). Split-bf16 (hi+lo) for a and Waa (3 MFMA
// terms), single bf16 for x@Wax and Wy. State relayout C->A via packed LDS
// (u32 = lo<<16|hi), double buffered => 1 barrier/step.
//
// MFMA layout assumptions (gfx950 mfma_f32_16x16x32_bf16):
//   A-frag: m = lane&15, k = 32*kbm + 8*(lane>>4) + j   (j = vector elem 0..7)
//   B-frag: n = lane&15, k = 32*kbm + 8*(lane>>4) + j
//   C/D   : col(n) = lane&15, row(m) = (lane>>4)*4 + reg   [doc-verified]

#define B_ 4096
#define T_ 256
#define E_ 27
#define H_ 64
#define ROWS_ 16

// LDS strides (elements), padded so 16-lane frag reads are <=2-way conflicts
#define SWAA_ 72  // uint16 stride: row byte stride 144 (16B aligned, odd*16)
#define SWAX_ 40  // uint16
#define SWY_  72  // uint16
#define SAP_  68  // uint32 stride: row byte stride 272 (16B aligned)

typedef __bf16 bf16x8 __attribute__((ext_vector_type(8)));
typedef float f32x4 __attribute__((ext_vector_type(4)));
typedef unsigned int u32x4 __attribute__((ext_vector_type(4)));

static __device__ __forceinline__ unsigned f2bf(float f) {
  unsigned u = __builtin_bit_cast(unsigned, f);
  return (u + 0x7FFFu + ((u >> 16) & 1u)) >> 16;  // RNE; inputs finite
}
static __device__ __forceinline__ float bf2f(unsigned h) {
  return __builtin_bit_cast(float, h << 16);
}
static __device__ __forceinline__ float fast_tanh(float z) {
  // tanh(z) = 1 - 2/(exp(2z)+1); exp->inf / ->0 limits give +/-1 correctly
  float e = __expf(2.0f * z);
  float r = __builtin_amdgcn_rcpf(e + 1.0f);
  return __builtin_fmaf(-2.0f, r, 1.0f);
}
static __device__ __forceinline__ f32x4 MF(bf16x8 a, u32x4 b, f32x4 c) {
  return __builtin_amdgcn_mfma_f32_16x16x32_bf16(
      a, __builtin_bit_cast(bf16x8, b), c, 0, 0, 0);
}

__global__ __launch_bounds__(256, 1) void rnn_fused(
    const float* __restrict__ word, const float* __restrict__ Wa,
    const float* __restrict__ ba, const float* __restrict__ Wy,
    const float* __restrict__ by, float* __restrict__ out) {
  __shared__ unsigned short sWaaH[H_][SWAA_];
  __shared__ unsigned short sWaaL[H_][SWAA_];
  __shared__ unsigned short sWax[H_][SWAX_];   // cols 27..31 zero
  __shared__ unsigned short sWy[32][SWY_];     // rows 27..31 zero
  __shared__ unsigned int sAp[2][ROWS_][SAP_]; // packed state: lo<<16|hi
  __shared__ float sBa[H_];
  __shared__ float sBy[32];

  const int tid = threadIdx.x;

  // ---- weight prep (per block; ~6K loads, trivial vs 256-step loop) ----
  for (int idx = tid; idx < H_ * H_; idx += 256) {
    const int i = idx >> 6, j = idx & 63;
    const float w = Wa[i * (H_ + E_) + j];  // Waa[i][j]
    const unsigned h = f2bf(w);
    sWaaH[i][j] = (unsigned short)h;
    sWaaL[i][j] = (unsigned short)f2bf(w - bf2f(h));
  }
  for (int idx = tid; idx < H_ * 32; idx += 256) {
    const int i = idx >> 5, k = idx & 31;
    sWax[i][k] = (unsigned short)((k < E_) ? f2bf(Wa[i * (H_ + E_) + H_ + k]) : 0u);
  }
  for (int idx = tid; idx < 32 * H_; idx += 256) {
    const int n = idx >> 6, j = idx & 63;
    sWy[n][j] = (unsigned short)((n < E_) ? f2bf(Wy[n * H_ + j]) : 0u);
  }
  if (tid < H_) sBa[tid] = ba[tid];
  if (tid < 32) sBy[tid] = (tid < E_) ? by[tid] : 0.0f;
  __syncthreads();

  const int wv = tid >> 6;   // N-tile 0..3
  const int ln = tid & 63;
  const int l16 = ln & 15;
  const int kb = ln >> 4;    // k-block within frag
  const int rb = (int)blockIdx.x * ROWS_;

  // B-frag pointers (loop-invariant; 16B aligned by stride choice)
  const u32x4* const bWaaH0 = (const u32x4*)&sWaaH[wv * 16 + l16][kb * 8];
  const u32x4* const bWaaH1 = (const u32x4*)&sWaaH[wv * 16 + l16][32 + kb * 8];
  const u32x4* const bWaaL0 = (const u32x4*)&sWaaL[wv * 16 + l16][kb * 8];
  const u32x4* const bWaaL1 = (const u32x4*)&sWaaL[wv * 16 + l16][32 + kb * 8];
  const u32x4* const bWax   = (const u32x4*)&sWax[wv * 16 + l16][kb * 8];

  const float bav = sBa[wv * 16 + l16];

  // per-lane word pointer: row rb+l16, k-slice kb*8 (+t*E_ per step)
  const float* const wrow = word + ((size_t)(rb + l16) * T_) * E_ + kb * 8;

  // y-phase state (waves 0,1 only; wave-uniform guard so MFMA is whole-wave)
  const u32x4* bWy0 = (const u32x4*)&sWy[(wv & 1) * 16 + l16][kb * 8];
  const u32x4* bWy1 = (const u32x4*)&sWy[(wv & 1) * 16 + l16][32 + kb * 8];
  const float byv = sBy[(wv & 1) * 16 + l16];
  const bool ystore = (wv < 2) && ((wv * 16 + l16) < E_);
  float* const orow = out + ((size_t)(rb + kb * 4) * T_) * E_ + (wv & 1) * 16 + l16;

  const u32x4 zu = {0u, 0u, 0u, 0u};
  bf16x8 aH0 = __builtin_bit_cast(bf16x8, zu);
  bf16x8 aH1 = aH0, aL0 = aH0, aL1 = aH0;
  u32x4 xu = zu;  // packed bf16 x-frag (pairs j even|odd<<16); 0 at t=0

  for (int t = 0; t < T_; ++t) {
    // ---- prefetch word[.,t,.] raw (this is x for iteration t+1) ----
    float xr0 = 0.f, xr1 = 0.f, xr2 = 0.f, xr3 = 0.f,
          xr4 = 0.f, xr5 = 0.f, xr6 = 0.f, xr7 = 0.f;
    {
      const float* p = wrow + t * E_;
      const int k0 = kb * 8;
      if (k0 + 0 < E_) xr0 = p[0];
      if (k0 + 1 < E_) xr1 = p[1];
      if (k0 + 2 < E_) xr2 = p[2];
      if (k0 + 3 < E_) xr3 = p[3];
      if (k0 + 4 < E_) xr4 = p[4];
      if (k0 + 5 < E_) xr5 = p[5];
      if (k0 + 6 < E_) xr6 = p[6];
      if (k0 + 7 < E_) xr7 = p[7];
    }

    // ---- pre-activation: two independent accumulation chains ----
    f32x4 accA = {bav, bav, bav, bav};
    f32x4 accB = {0.f, 0.f, 0.f, 0.f};
    const bf16x8 xf = __builtin_bit_cast(bf16x8, xu);
    accA = MF(aH0, *bWaaH0, accA);
    accB = MF(aH1, *bWaaH1, accB);
    accA = MF(aL0, *bWaaH0, accA);
    accB = MF(aL1, *bWaaH1, accB);
    accA = MF(aH0, *bWaaL0, accA);
    accB = MF(aH1, *bWaaL1, accB);
    accA = MF(xf, *bWax, accA);
    const f32x4 acc = accA + accB;

    // ---- tanh, split to hi/lo bf16, pack, stash in LDS ----
    const int buf = t & 1;
#pragma unroll
    for (int c = 0; c < 4; ++c) {
      const float na = fast_tanh(acc[c]);
      const unsigned h = f2bf(na);
      const unsigned l = f2bf(na - bf2f(h));
      sAp[buf][kb * 4 + c][wv * 16 + l16] = (l << 16) | h;  // row, col=i
    }
    __syncthreads();

    // ---- read state back in A-frag layout, unpack via v_perm ----
    const u32x4 s0 = *(const u32x4*)&sAp[buf][l16][kb * 8];
    const u32x4 s1 = *(const u32x4*)&sAp[buf][l16][kb * 8 + 4];
    const u32x4 s2 = *(const u32x4*)&sAp[buf][l16][32 + kb * 8];
    const u32x4 s3 = *(const u32x4*)&sAp[buf][l16][32 + kb * 8 + 4];
    u32x4 h0, l0, h1, l1;
    h0[0] = __builtin_amdgcn_perm(s0[1], s0[0], 0x05040100u);
    h0[1] = __builtin_amdgcn_perm(s0[3], s0[2], 0x05040100u);
    h0[2] = __builtin_amdgcn_perm(s1[1], s1[0], 0x05040100u);
    h0[3] = __builtin_amdgcn_perm(s1[3], s1[2], 0x05040100u);
    l0[0] = __builtin_amdgcn_perm(s0[1], s0[0], 0x07060302u);
    l0[1] = __builtin_amdgcn_perm(s0[3], s0[2], 0x07060302u);
    l0[2] = __builtin_amdgcn_perm(s1[1], s1[0], 0x07060302u);
    l0[3] = __builtin_amdgcn_perm(s1[3], s1[2], 0x07060302u);
    h1[0] = __builtin_amdgcn_perm(s2[1], s2[0], 0x05040100u);
    h1[1] = __builtin_amdgcn_perm(s2[3], s2[2], 0x05040100u);
    h1[2] = __builtin_amdgcn_perm(s3[1], s3[0], 0x05040100u);
    h1[3] = __builtin_amdgcn_perm(s3[3], s3[2], 0x05040100u);
    l1[0] = __builtin_amdgcn_perm(s2[1], s2[0], 0x07060302u);
    l1[1] = __builtin_amdgcn_perm(s2[3], s2[2], 0x07060302u);
    l1[2] = __builtin_amdgcn_perm(s3[1], s3[0], 0x07060302u);
    l1[3] = __builtin_amdgcn_perm(s3[3], s3[2], 0x07060302u);
    aH0 = __builtin_bit_cast(bf16x8, h0);
    aL0 = __builtin_bit_cast(bf16x8, l0);
    aH1 = __builtin_bit_cast(bf16x8, h1);
    aL1 = __builtin_bit_cast(bf16x8, l1);

    // ---- y = na @ Wy^T + by (waves 0,1; uniform branch) ----
    if (wv < 2) {
      f32x4 y = {byv, byv, byv, byv};
      y = MF(aH0, *bWy0, y);
      y = MF(aH1, *bWy1, y);
      if (ystore) {
        float* p = orow + t * E_;
        p[0 * T_ * E_] = y[0];
        p[1 * T_ * E_] = y[1];
        p[2 * T_ * E_] = y[2];
        p[3 * T_ * E_] = y[3];
      }
    }

    // ---- convert prefetched x to packed bf16 frag for next step ----
    xu[0] = f2bf(xr0) | (f2bf(xr1) << 16);
    xu[1] = f2bf(xr2) | (f2bf(xr3) << 16);
    xu[2] = f2bf(xr4) | (f2bf(xr5) << 16);
    xu[3] = f2bf(xr6) | (f2bf(xr7) << 16);
    // no second barrier: sAp is double-buffered (next iter writes buf^1)
  }
}

extern "C" void kernel_launch(void* const* d_in, const int* in_sizes, int n_in,
                              void* d_out, int out_size, void* d_ws,
                              size_t ws_size, hipStream_t stream) {
  const float* word = (const float*)d_in[0];
  const float* Wa = (const float*)d_in[1];
  const float* ba = (const float*)d_in[2];
  const float* Wy = (const float*)d_in[3];
  const float* by = (const float*)d_in[4];
  float* out = (float*)d_out;
  rnn_fused<<<dim3(B_ / ROWS_), dim3(256), 0, stream>>>(word, Wa, ba, Wy, by, out);
}

// Round 2
// 231.559 us; speedup vs baseline: 1.1070x; 1.1070x over previous
//
#include <hip/hip_runtime.h>
#include <stdint.h>

// RNN1: B=4096,T=256,E=27,H=64.
// a_{t+1} = tanh(a_t @ Waa^T + x_t @ Wax^T + ba), x_t = word[:,t-1,:] (0 at t=0)
// y[:,t,:] = a_{t+1} @ Wy^T + by
//
// Round 2: same 256x256 mapping (16 rows/block, wave wv owns hidden N-tile).
// Changes vs round 1:
//  - raw s_barrier + lgkmcnt(0) only (no vmcnt drain): x loads / y stores stay
//    in flight across the per-step barrier.
//  - weight fragments hoisted to registers (were 5 conflicted LDS reads/step).
//  - state LDS buffer XOR-swizzled (T2): word(row,col) = row*64 + (col ^ ((row&7)<<2))
//  - MFMA accumulation restructured to depth-2 chains (4 accs + tree add).
//  - x pack moved to top of next iteration (full-step latency slack).

#define B_ 4096
#define T_ 256
#define E_ 27
#define H_ 64
#define ROWS_ 16

typedef __bf16 bf16x8 __attribute__((ext_vector_type(8)));
typedef float f32x4 __attribute__((ext_vector_type(4)));
typedef unsigned int u32x4 __attribute__((ext_vector_type(4)));

static __device__ __forceinline__ unsigned f2bf(float f) {
  unsigned u = __builtin_bit_cast(unsigned, f);
  return (u + 0x7FFFu + ((u >> 16) & 1u)) >> 16;  // RNE; inputs finite
}
static __device__ __forceinline__ float bf2f(unsigned h) {
  return __builtin_bit_cast(float, h << 16);
}
static __device__ __forceinline__ float fast_tanh(float z) {
  float e = __expf(2.0f * z);
  float r = __builtin_amdgcn_rcpf(e + 1.0f);
  return __builtin_fmaf(-2.0f, r, 1.0f);
}
static __device__ __forceinline__ f32x4 MF(bf16x8 a, u32x4 b, f32x4 c) {
  return __builtin_amdgcn_mfma_f32_16x16x32_bf16(
      a, __builtin_bit_cast(bf16x8, b), c, 0, 0, 0);
}

__global__ __launch_bounds__(256, 1) void rnn_fused(
    const float* __restrict__ word, const float* __restrict__ Wa,
    const float* __restrict__ ba, const float* __restrict__ Wy,
    const float* __restrict__ by, float* __restrict__ out) {
  // weight staging (preamble only; strides 16B-aligned)
  __shared__ unsigned short sWaaH[H_][72];
  __shared__ unsigned short sWaaL[H_][72];
  __shared__ unsigned short sWax[H_][40];   // cols 27..31 zero
  __shared__ unsigned short sWy[32][72];    // rows 27..31 zero
  __shared__ unsigned int sAp[2 * ROWS_ * 64];  // packed state lo<<16|hi, swizzled
  __shared__ float sBa[H_];
  __shared__ float sBy[32];

  const int tid = threadIdx.x;

  for (int idx = tid; idx < H_ * H_; idx += 256) {
    const int i = idx >> 6, j = idx & 63;
    const float w = Wa[i * (H_ + E_) + j];  // Waa[i][j]
    const unsigned h = f2bf(w);
    sWaaH[i][j] = (unsigned short)h;
    sWaaL[i][j] = (unsigned short)f2bf(w - bf2f(h));
  }
  for (int idx = tid; idx < H_ * 32; idx += 256) {
    const int i = idx >> 5, k = idx & 31;
    sWax[i][k] = (unsigned short)((k < E_) ? f2bf(Wa[i * (H_ + E_) + H_ + k]) : 0u);
  }
  for (int idx = tid; idx < 32 * H_; idx += 256) {
    const int n = idx >> 6, j = idx & 63;
    sWy[n][j] = (unsigned short)((n < E_) ? f2bf(Wy[n * H_ + j]) : 0u);
  }
  if (tid < H_) sBa[tid] = ba[tid];
  if (tid < 32) sBy[tid] = (tid < E_) ? by[tid] : 0.0f;
  __syncthreads();

  const int wv = tid >> 6;   // N-tile 0..3
  const int ln = tid & 63;
  const int l16 = ln & 15;
  const int kb = ln >> 4;    // k-block within frag
  const int rb = (int)blockIdx.x * ROWS_;

  // ---- hoist weight fragments to registers (loop-invariant) ----
  const u32x4 fWaaH0 = *(const u32x4*)&sWaaH[wv * 16 + l16][kb * 8];
  const u32x4 fWaaH1 = *(const u32x4*)&sWaaH[wv * 16 + l16][32 + kb * 8];
  const u32x4 fWaaL0 = *(const u32x4*)&sWaaL[wv * 16 + l16][kb * 8];
  const u32x4 fWaaL1 = *(const u32x4*)&sWaaL[wv * 16 + l16][32 + kb * 8];
  const u32x4 fWax   = *(const u32x4*)&sWax[wv * 16 + l16][kb * 8];
  const u32x4 fWy0   = *(const u32x4*)&sWy[(wv & 1) * 16 + l16][kb * 8];
  const u32x4 fWy1   = *(const u32x4*)&sWy[(wv & 1) * 16 + l16][32 + kb * 8];

  const float bav = sBa[wv * 16 + l16];
  const float byv = sBy[(wv & 1) * 16 + l16];

  // ---- state-buffer word offsets (XOR swizzle, stride 64 words) ----
  // word(row,col) = row*64 + (col ^ ((row&7)<<2)); 4-word blocks stay contiguous
  const int swzR = (l16 & 7) << 2;
  const int r0 = l16 * 64 + ((kb * 8 + 0) ^ swzR);
  const int r1 = l16 * 64 + ((kb * 8 + 4) ^ swzR);
  const int r2 = l16 * 64 + ((kb * 8 + 32) ^ swzR);
  const int r3 = l16 * 64 + ((kb * 8 + 36) ^ swzR);
  const int colw = wv * 16 + l16;
  const int w0 = (kb * 4 + 0) * 64 + (colw ^ (((kb * 4 + 0) & 7) << 2));
  const int w1 = (kb * 4 + 1) * 64 + (colw ^ (((kb * 4 + 1) & 7) << 2));
  const int w2 = (kb * 4 + 2) * 64 + (colw ^ (((kb * 4 + 2) & 7) << 2));
  const int w3 = (kb * 4 + 3) * 64 + (colw ^ (((kb * 4 + 3) & 7) << 2));

  // per-lane word pointer: row rb+l16, k-slice kb*8 (+t*E_ per step)
  const float* const wrow = word + ((size_t)(rb + l16) * T_) * E_ + kb * 8;
  const bool ystore = (wv < 2) && ((wv * 16 + l16) < E_);
  float* const orow = out + ((size_t)(rb + kb * 4) * T_) * E_ + (wv & 1) * 16 + l16;

  const u32x4 zu = {0u, 0u, 0u, 0u};
  const f32x4 zf = {0.f, 0.f, 0.f, 0.f};
  bf16x8 aH0 = __builtin_bit_cast(bf16x8, zu);
  bf16x8 aH1 = aH0, aL0 = aH0, aL1 = aH0;
  // x raw prefetch regs; zero so t=0 packs x=0
  float xr0 = 0.f, xr1 = 0.f, xr2 = 0.f, xr3 = 0.f,
        xr4 = 0.f, xr5 = 0.f, xr6 = 0.f, xr7 = 0.f;

  for (int t = 0; t < T_; ++t) {
    // ---- pack x (loaded a full iteration ago; t=0: zeros) ----
    u32x4 xu;
    xu[0] = f2bf(xr0) | (f2bf(xr1) << 16);
    xu[1] = f2bf(xr2) | (f2bf(xr3) << 16);
    xu[2] = f2bf(xr4) | (f2bf(xr5) << 16);
    xu[3] = f2bf(xr6) | (f2bf(xr7) << 16);
    const bf16x8 xf = __builtin_bit_cast(bf16x8, xu);

    // ---- issue next x prefetch (word[.,t,.] = x for step t+1) ----
    {
      const float* p = wrow + t * E_;
      const int k0 = kb * 8;
      xr0 = (k0 + 0 < E_) ? p[0] : 0.f;
      xr1 = (k0 + 1 < E_) ? p[1] : 0.f;
      xr2 = (k0 + 2 < E_) ? p[2] : 0.f;
      xr3 = (k0 + 3 < E_) ? p[3] : 0.f;
      xr4 = (k0 + 4 < E_) ? p[4] : 0.f;
      xr5 = (k0 + 5 < E_) ? p[5] : 0.f;
      xr6 = (k0 + 6 < E_) ? p[6] : 0.f;
      xr7 = (k0 + 7 < E_) ? p[7] : 0.f;
    }

    // ---- pre-activation: depth-2 MFMA chains ----
    f32x4 c0 = {bav, bav, bav, bav};
    c0 = MF(aH0, fWaaH0, c0);
    c0 = MF(aL0, fWaaH0, c0);
    f32x4 c1 = MF(aH1, fWaaH1, zf);
    c1 = MF(aL1, fWaaH1, c1);
    f32x4 c2 = MF(aH0, fWaaL0, zf);
    c2 = MF(xf, fWax, c2);
    f32x4 c3 = MF(aH1, fWaaL1, zf);
    const f32x4 acc = (c0 + c1) + (c2 + c3);

    // ---- tanh, split hi/lo, pack, stash (swizzled, double-buffered) ----
    const int bb = (t & 1) << 10;  // 1024 words per buffer
    {
      const float n0 = fast_tanh(acc[0]);
      const unsigned h = f2bf(n0), l = f2bf(n0 - bf2f(h));
      sAp[bb + w0] = (l << 16) | h;
    }
    {
      const float n1 = fast_tanh(acc[1]);
      const unsigned h = f2bf(n1), l = f2bf(n1 - bf2f(h));
      sAp[bb + w1] = (l << 16) | h;
    }
    {
      const float n2 = fast_tanh(acc[2]);
      const unsigned h = f2bf(n2), l = f2bf(n2 - bf2f(h));
      sAp[bb + w2] = (l << 16) | h;
    }
    {
      const float n3 = fast_tanh(acc[3]);
      const unsigned h = f2bf(n3), l = f2bf(n3 - bf2f(h));
      sAp[bb + w3] = (l << 16) | h;
    }

    // ---- barrier WITHOUT vmcnt drain (x loads / y stores stay in flight) ----
    asm volatile("s_waitcnt lgkmcnt(0)" ::: "memory");
    __builtin_amdgcn_sched_barrier(0);
    __builtin_amdgcn_s_barrier();
    __builtin_amdgcn_sched_barrier(0);

    // ---- read state back in A-frag layout, unpack via v_perm ----
    const u32x4 s0 = *(const u32x4*)&sAp[bb + r0];
    const u32x4 s1 = *(const u32x4*)&sAp[bb + r1];
    const u32x4 s2 = *(const u32x4*)&sAp[bb + r2];
    const u32x4 s3 = *(const u32x4*)&sAp[bb + r3];
    u32x4 h0, l0, h1, l1;
    h0[0] = __builtin_amdgcn_perm(s0[1], s0[0], 0x05040100u);
    h0[1] = __builtin_amdgcn_perm(s0[3], s0[2], 0x05040100u);
    h0[2] = __builtin_amdgcn_perm(s1[1], s1[0], 0x05040100u);
    h0[3] = __builtin_amdgcn_perm(s1[3], s1[2], 0x05040100u);
    l0[0] = __builtin_amdgcn_perm(s0[1], s0[0], 0x07060302u);
    l0[1] = __builtin_amdgcn_perm(s0[3], s0[2], 0x07060302u);
    l0[2] = __builtin_amdgcn_perm(s1[1], s1[0], 0x07060302u);
    l0[3] = __builtin_amdgcn_perm(s1[3], s1[2], 0x07060302u);
    h1[0] = __builtin_amdgcn_perm(s2[1], s2[0], 0x05040100u);
    h1[1] = __builtin_amdgcn_perm(s2[3], s2[2], 0x05040100u);
    h1[2] = __builtin_amdgcn_perm(s3[1], s3[0], 0x05040100u);
    h1[3] = __builtin_amdgcn_perm(s3[3], s3[2], 0x05040100u);
    l1[0] = __builtin_amdgcn_perm(s2[1], s2[0], 0x07060302u);
    l1[1] = __builtin_amdgcn_perm(s2[3], s2[2], 0x07060302u);
    l1[2] = __builtin_amdgcn_perm(s3[1], s3[0], 0x07060302u);
    l1[3] = __builtin_amdgcn_perm(s3[3], s3[2], 0x07060302u);
    aH0 = __builtin_bit_cast(bf16x8, h0);
    aL0 = __builtin_bit_cast(bf16x8, l0);
    aH1 = __builtin_bit_cast(bf16x8, h1);
    aL1 = __builtin_bit_cast(bf16x8, l1);

    // ---- y = na @ Wy^T + by (waves 0,1; uniform branch) ----
    if (wv < 2) {
      f32x4 y = {byv, byv, byv, byv};
      y = MF(aH0, fWy0, y);
      y = MF(aH1, fWy1, y);
      if (ystore) {
        float* p = orow + t * E_;
        p[0 * T_ * E_] = y[0];
        p[1 * T_ * E_] = y[1];
        p[2 * T_ * E_] = y[2];
        p[3 * T_ * E_] = y[3];
      }
    }
    // no second barrier: double-buffered sAp; a wave cannot pass two barriers
    // while another still reads (its reads retire at its own lgkmcnt(0)).
  }
}

extern "C" void kernel_launch(void* const* d_in, const int* in_sizes, int n_in,
                              void* d_out, int out_size, void* d_ws,
                              size_t ws_size, hipStream_t stream) {
  const float* word = (const float*)d_in[0];
  const float* Wa = (const float*)d_in[1];
  const float* ba = (const float*)d_in[2];
  const float* Wy = (const float*)d_in[3];
  const float* by = (const float*)d_in[4];
  float* out = (float*)d_out;
  rnn_fused<<<dim3(B_ / ROWS_), dim3(256), 0, stream>>>(word, Wa, ba, Wy, by, out);
}